// Round 9
// baseline (329.485 us; speedup 1.0000x reference)
//
#include <hip/hip_runtime.h>
#include <math.h>

#define DIM 64
#define SEQ 784
#define BATCH 256
// 7 groups x 112 rows. Within a group, processing index m = 0..111 maps to
// t = T0 - m (T0 = 783-112g), LDS row r = 111 - m.

// ---------- cross-lane helpers (wave64 reduction via DPP) ----------
template <int CTRL>
__device__ __forceinline__ float dpp_add_step(float s) {
    int v = __builtin_amdgcn_update_dpp(0, __float_as_int(s), CTRL, 0xF, 0xF, false);
    return s + __int_as_float(v);
}

// Sum across all 64 lanes; result broadcast (uniform, via readlane 63).
__device__ __forceinline__ float wave_allsum(float x) {
    x = dpp_add_step<0xB1>(x);   // xor 1
    x = dpp_add_step<0x4E>(x);   // xor 2
    x = dpp_add_step<0x141>(x);  // row_half_mirror
    x = dpp_add_step<0x140>(x);  // row_mirror
    x = dpp_add_step<0x142>(x);  // row_bcast15
    x = dpp_add_step<0x143>(x);  // row_bcast31
    return __int_as_float(__builtin_amdgcn_readlane(__float_as_int(x), 63));
}

// 16-lane row allsum: uniform within each 16-lane row, 4 DPP steps, no readlane.
__device__ __forceinline__ float row16_allsum(float x) {
    x = dpp_add_step<0xB1>(x);
    x = dpp_add_step<0x4E>(x);
    x = dpp_add_step<0x141>(x);
    x = dpp_add_step<0x140>(x);
    return x;
}

__device__ __forceinline__ float dot4(float4 a, float4 b) {
    return fmaf(a.w, b.w, fmaf(a.z, b.z, fmaf(a.y, b.y, a.x * b.x)));
}

__device__ __forceinline__ float gelu_exact(float v) {
    return 0.5f * v * (1.0f + erff(v * 0.70710678118654752440f));
}

// Zero-instruction wave-local LDS ordering (compile-time only; same-wave DS
// ops complete in order in HW). Validated R5-R8.
#define WAVE_FENCE()                                                \
    do {                                                            \
        __builtin_amdgcn_wave_barrier();                            \
        asm volatile("" ::: "memory");                              \
    } while (0)

// ---------- fused kernel: one block (8 waves) per batch ----------
// Per group period:
//   phase1: wave0 D-batch (112 indep. reductions) || waves1-7 Gram (6216 dots)
//   __syncthreads
//   phase2: wave0 substitution (+u update)        || waves1-7 produce(g+1)
//   __syncthreads
__global__ __launch_bounds__(512, 1) void fused_all(
    const float* __restrict__ x, const float* __restrict__ W_in,
    const float* __restrict__ pos_emb, const float* __restrict__ Wq,
    const float* __restrict__ Wk, const float* __restrict__ Wv,
    const float* __restrict__ Wb, const float* __restrict__ bbp,
    const float* __restrict__ ln_g, const float* __restrict__ ln_b,
    const float* __restrict__ Wc, const float* __restrict__ bc,
    float* __restrict__ out)
{
    const int lane = threadIdx.x & 63;
    const int wv   = threadIdx.x >> 6;     // 0..7
    const int b    = blockIdx.x;

    __shared__ __align__(16) float kbuf[2][112][64];   // 57,344 B
    __shared__ __align__(16) float G_pk[6280];         // packed lower-tri Gram (+pad)
    __shared__ __align__(16) float al_lds[SEQ];        // alpha (absolute t)
    __shared__ __align__(16) float a_lds[SEQ];         // a output (absolute t)
    __shared__ __align__(16) float D_lds[128];         // D bounce (padded)
    __shared__ __align__(16) float hbuf[8][2][64];     // per-wave h scratch
    __shared__ __align__(16) float sh[64];
    __shared__ __align__(16) float swr[8][64];

    const float win = W_in[lane];
    float4 wkr[16];
    {
        const float4* wk4 = (const float4*)(Wk + lane * 64);
#pragma unroll
        for (int i = 0; i < 16; ++i) wkr[i] = wk4[i];
    }
    const float wb = Wb[lane];
    const float bb = bbp[0];

    // ---- producer: 16 rows of group g, 2-row interleaved for ILP ----
    auto produce = [&](int g, int buf) {
        const int base = 672 - 112 * g;
        const int r0   = (wv - 1) * 16;
#pragma unroll 1
        for (int i = 0; i < 8; ++i) {
            const int rA = r0 + i, rB = r0 + i + 8;
            const int sA = base + rA, sB = base + rB;
            const float hA = gelu_exact(fmaf(x[b * SEQ + sA], win, pos_emb[sA * 64 + lane]));
            const float hB = gelu_exact(fmaf(x[b * SEQ + sB], win, pos_emb[sB * 64 + lane]));
            const float bdA = wave_allsum(hA * wb);
            const float bdB = wave_allsum(hB * wb);
            hbuf[wv][0][lane] = hA;
            hbuf[wv][1][lane] = hB;
            WAVE_FENCE();
            const float4* hA4 = (const float4*)hbuf[wv][0];
            const float4* hB4 = (const float4*)hbuf[wv][1];
            float kdA = 0.f, kdB = 0.f;
#pragma unroll
            for (int j = 0; j < 16; ++j) {
                const float4 ha = hA4[j], hb2 = hB4[j], wk = wkr[j];
                kdA = fmaf(ha.x, wk.x, kdA);  kdB = fmaf(hb2.x, wk.x, kdB);
                kdA = fmaf(ha.y, wk.y, kdA);  kdB = fmaf(hb2.y, wk.y, kdB);
                kdA = fmaf(ha.z, wk.z, kdA);  kdB = fmaf(hb2.z, wk.z, kdB);
                kdA = fmaf(ha.w, wk.w, kdA);  kdB = fmaf(hb2.w, wk.w, kdB);
            }
            const float lamA = fmaxf(wave_allsum(kdA * kdA), 1e-6f);
            const float lamB = fmaxf(wave_allsum(kdB * kdB), 1e-6f);
            const float beA = 1.0f / (1.0f + expf(-(bdA + bb)));
            const float beB = 1.0f / (1.0f + expf(-(bdB + bb)));
            const float alA = -expm1f(-beA * lamA) / (lamA + 1e-6f);
            const float alB = -expm1f(-beB * lamB) / (lamB + 1e-6f);
            kbuf[buf][rA][lane] = kdA;
            kbuf[buf][rB][lane] = kdB;
            if (lane == 0) { al_lds[sA] = alA; al_lds[sB] = alB; }
            WAVE_FENCE();              // reads done before next iter's writes
        }
    };

    // ---- producer: packed Gram of current buf. Row m' holds G_{m',m}, m>m',
    // at G_pk[off(m') + m-m'-1], off(m') = 111m' - m'(m'-1)/2. 4 entries/iter.
    auto gram = [&](int buf) {
#pragma unroll 1
        for (int mp = wv - 1; mp <= 110; mp += 7) {
            const int offp = 111 * mp - (mp * (mp - 1)) / 2;
            const float4 kA = ((const float4*)kbuf[buf][111 - mp])[lane & 15];
#pragma unroll 1
            for (int mb = mp + 1; mb <= 111; mb += 4) {
                const int m    = mb + (lane >> 4);
                const int mc   = (m <= 111) ? m : 111;
                const float4 kB = ((const float4*)kbuf[buf][111 - mc])[lane & 15];
                const float gv = row16_allsum(dot4(kA, kB));
                if ((lane & 15) == 0 && m <= 111)
                    G_pk[offp + (m - mp - 1)] = gv;
            }
        }
    };

    // ---- phase 0: wave0 u-init || producers produce(group 0) ----
    float4 uq = make_float4(0.f, 0.f, 0.f, 0.f);
    if (wv == 0) {
        const float h = gelu_exact(fmaf(x[b * SEQ + 783], win, pos_emb[783 * 64 + lane]));
        sh[lane] = h;
        WAVE_FENCE();
        float u = 0.f;
        const float4* wq4 = (const float4*)(Wq + lane * 64);
        const float4* h4  = (const float4*)sh;
#pragma unroll
        for (int i = 0; i < 16; ++i) {
            float4 hv = h4[i], qv = wq4[i];
            u = fmaf(hv.x, qv.x, u);
            u = fmaf(hv.y, qv.y, u);
            u = fmaf(hv.z, qv.z, u);
            u = fmaf(hv.w, qv.w, u);
        }
        WAVE_FENCE();
        sh[lane] = u;
        WAVE_FENCE();
        uq = ((const float4*)sh)[lane & 15];   // replicated slice layout
    } else {
        produce(0, 0);
    }
    __syncthreads();

    // ---- main loop over 7 groups ----
#pragma unroll 1
    for (int g = 0; g < 7; ++g) {
        const int buf = g & 1;
        const int T0  = 783 - 112 * g;

        // phase 1: D-batch (wave0) || Gram (producers)
        if (wv == 0) {
#pragma unroll 1
            for (int mb = 0; mb < 112; mb += 4) {
                const int m = mb + (lane >> 4);
                const float4 kk = ((const float4*)kbuf[buf][111 - m])[lane & 15];
                const float D = row16_allsum(dot4(uq, kk));
                if ((lane & 15) == 0) D_lds[m] = D;
            }
        } else {
            gram(buf);
        }
        __syncthreads();

        // phase 2: substitution + u-update (wave0) || produce(g+1) (producers)
        if (wv == 0) {
            float Dr0 = D_lds[lane];
            float Dr1 = (lane < 48) ? D_lds[64 + lane] : 0.f;
            float a_v0 = 0.f, a_v1 = 0.f;
            int off = 0;
            // steps m = 0..63 (remaining-D in Dr0 and Dr1)
#pragma unroll 4
            for (int m = 0; m < 64; ++m) {
                const float alv = al_lds[T0 - m];
                const float Dm  = __int_as_float(
                    __builtin_amdgcn_readlane(__float_as_int(Dr0), m));
                const float a = alv * Dm;
                a_v0 = (lane == m) ? a : a_v0;
                const int d0 = lane - m - 1;
                const int i0 = off + (d0 > 0 ? d0 : 0);
                const int i1 = off + 63 + lane - m;
                const float g0 = G_pk[i0];
                const float g1 = G_pk[i1];
                if (lane > m)  Dr0 = fmaf(-a, g0, Dr0);
                if (lane < 48) Dr1 = fmaf(-a, g1, Dr1);
                off += 111 - m;
            }
            // steps m = 64..111 (remaining-D only in Dr1)
#pragma unroll 4
            for (int m = 64; m < 112; ++m) {
                const float alv = al_lds[T0 - m];
                const float Dm  = __int_as_float(
                    __builtin_amdgcn_readlane(__float_as_int(Dr1), m - 64));
                const float a = alv * Dm;
                a_v1 = (lane == m - 64) ? a : a_v1;
                const int d1 = 63 + lane - m;
                const int i1 = off + (d1 > 0 ? d1 : 0);
                const float g1 = G_pk[i1];
                if (lane > m - 64 && lane < 48) Dr1 = fmaf(-a, g1, Dr1);
                off += 111 - m;
            }
            // dump a's (lane-parallel, distinct addresses)
            a_lds[T0 - lane] = a_v0;
            if (lane < 48) a_lds[T0 - 64 - lane] = a_v1;
            WAVE_FENCE();
            // u-update: uq -= sum_m a_m * k_m  (4 steps per iter)
#pragma unroll 1
            for (int mb = 0; mb < 112; mb += 4) {
                const float4 av = *(const float4*)&a_lds[T0 - mb - 3];
                // av.w=a_mb, av.z=a_{mb+1}, av.y=a_{mb+2}, av.x=a_{mb+3}
                const float4 k0 = ((const float4*)kbuf[buf][111 - mb])[lane & 15];
                const float4 k1 = ((const float4*)kbuf[buf][110 - mb])[lane & 15];
                const float4 k2 = ((const float4*)kbuf[buf][109 - mb])[lane & 15];
                const float4 k3 = ((const float4*)kbuf[buf][108 - mb])[lane & 15];
                uq.x = fmaf(-av.x, k3.x, fmaf(-av.y, k2.x, fmaf(-av.z, k1.x, fmaf(-av.w, k0.x, uq.x))));
                uq.y = fmaf(-av.x, k3.y, fmaf(-av.y, k2.y, fmaf(-av.z, k1.y, fmaf(-av.w, k0.y, uq.y))));
                uq.z = fmaf(-av.x, k3.z, fmaf(-av.y, k2.z, fmaf(-av.z, k1.z, fmaf(-av.w, k0.z, uq.z))));
                uq.w = fmaf(-av.x, k3.w, fmaf(-av.y, k2.w, fmaf(-av.z, k1.w, fmaf(-av.w, k0.w, uq.w))));
            }
        } else if (g < 6) {
            produce(g + 1, buf ^ 1);
        }
        __syncthreads();
    }

    // ---- wsum: all 8 waves, 98 rows each ----
    float w = 0.f;
    {
        const int t0 = wv * 98;
#pragma unroll 2
        for (int i = 0; i < 98; ++i) {
            const int t = t0 + i;
            const float h = gelu_exact(fmaf(x[b * SEQ + t], win, pos_emb[t * 64 + lane]));
            w = fmaf(a_lds[t], h, w);
        }
    }
    swr[wv][lane] = w;
    __syncthreads();
    if (wv != 0) return;

    // ---- wave-0 epilogue: last = Wv*w -> LN -> logits ----
    w = swr[0][lane] + swr[1][lane] + swr[2][lane] + swr[3][lane]
      + swr[4][lane] + swr[5][lane] + swr[6][lane] + swr[7][lane];
    sh[lane] = w;
    WAVE_FENCE();
    float last = 0.f;
    const float4* wv4 = (const float4*)(Wv + lane * 64);
    const float4* w4  = (const float4*)sh;
#pragma unroll
    for (int i = 0; i < 16; ++i) {
        float4 hv = w4[i], vv = wv4[i];
        last = fmaf(hv.x, vv.x, last);
        last = fmaf(hv.y, vv.y, last);
        last = fmaf(hv.z, vv.z, last);
        last = fmaf(hv.w, vv.w, last);
    }
    const float mu  = wave_allsum(last) * 0.015625f;
    const float dd  = last - mu;
    const float var = wave_allsum(dd * dd) * 0.015625f;
    const float ln  = dd / sqrtf(var + 1e-5f) * ln_g[lane] + ln_b[lane];
    WAVE_FENCE();
    sh[lane] = ln;
    WAVE_FENCE();
    if (lane < 10) {
        float acc = bc[lane];
        const float* wc = Wc + lane * 64;
#pragma unroll
        for (int j = 0; j < 64; ++j) acc = fmaf(wc[j], sh[j], acc);
        out[b * 10 + lane] = acc;
    }
}

extern "C" void kernel_launch(void* const* d_in, const int* in_sizes, int n_in,
                              void* d_out, int out_size, void* d_ws, size_t ws_size,
                              hipStream_t stream)
{
    const float* x       = (const float*)d_in[0];
    const float* W_in    = (const float*)d_in[1];
    const float* pos_emb = (const float*)d_in[2];
    const float* Wq      = (const float*)d_in[3];
    const float* Wk      = (const float*)d_in[4];
    const float* Wv      = (const float*)d_in[5];
    const float* Wb      = (const float*)d_in[6];
    const float* bb      = (const float*)d_in[7];
    const float* ln_g    = (const float*)d_in[8];
    const float* ln_b    = (const float*)d_in[9];
    const float* Wc      = (const float*)d_in[10];
    const float* bc      = (const float*)d_in[11];
    float* out = (float*)d_out;

    fused_all<<<BATCH, 512, 0, stream>>>(x, W_in, pos_emb, Wq, Wk, Wv, Wb, bb,
                                         ln_g, ln_b, Wc, bc, out);
}

// Round 10
// 131.091 us; speedup vs baseline: 2.5134x; 2.5134x over previous
//
#include <hip/hip_runtime.h>
#include <math.h>

#define DIM 64
#define SEQ 784
#define BATCH 256
// 7 groups x 112 rows; group split into 14 blocks of 8 steps.
// step m (0..111) -> t = T0 - m (T0 = 783-112g), LDS row r = 111 - m.

// ---------- cross-lane helpers (wave64 reduction via DPP) ----------
template <int CTRL>
__device__ __forceinline__ float dpp_add_step(float s) {
    int v = __builtin_amdgcn_update_dpp(0, __float_as_int(s), CTRL, 0xF, 0xF, false);
    return s + __int_as_float(v);
}

// Sum across all 64 lanes; result broadcast (uniform, via readlane 63).
__device__ __forceinline__ float wave_allsum(float x) {
    x = dpp_add_step<0xB1>(x);   // xor 1
    x = dpp_add_step<0x4E>(x);   // xor 2
    x = dpp_add_step<0x141>(x);  // row_half_mirror
    x = dpp_add_step<0x140>(x);  // row_mirror
    x = dpp_add_step<0x142>(x);  // row_bcast15
    x = dpp_add_step<0x143>(x);  // row_bcast31
    return __int_as_float(__builtin_amdgcn_readlane(__float_as_int(x), 63));
}

// 16-lane row allsum (replicated layout): 4 DPP steps, uniform result, no readlane.
__device__ __forceinline__ float row16_allsum(float x) {
    x = dpp_add_step<0xB1>(x);
    x = dpp_add_step<0x4E>(x);
    x = dpp_add_step<0x141>(x);
    x = dpp_add_step<0x140>(x);
    return x;
}

__device__ __forceinline__ float dot4(float4 a, float4 b) {
    return fmaf(a.w, b.w, fmaf(a.z, b.z, fmaf(a.y, b.y, a.x * b.x)));
}

__device__ __forceinline__ float gelu_exact(float v) {
    return 0.5f * v * (1.0f + erff(v * 0.70710678118654752440f));
}

// Zero-instruction wave-local LDS ordering (compile-time only; same-wave DS
// ops complete in order in HW). Validated R5-R8.
#define WAVE_FENCE()                                                \
    do {                                                            \
        __builtin_amdgcn_wave_barrier();                            \
        asm volatile("" ::: "memory");                              \
    } while (0)

// ---------- fused kernel: one block (8 waves) per batch ----------
// wave 0: scanner (oct-Gram blocks; Gram precomputed by producers)
// waves 1-7: produce(g+1) then gram8(g+1) on their OWN rows (wave-local).
__global__ __launch_bounds__(512, 1) void fused_all(
    const float* __restrict__ x, const float* __restrict__ W_in,
    const float* __restrict__ pos_emb, const float* __restrict__ Wq,
    const float* __restrict__ Wk, const float* __restrict__ Wv,
    const float* __restrict__ Wb, const float* __restrict__ bbp,
    const float* __restrict__ ln_g, const float* __restrict__ ln_b,
    const float* __restrict__ Wc, const float* __restrict__ bc,
    float* __restrict__ out)
{
    const int lane = threadIdx.x & 63;
    const int wv   = threadIdx.x >> 6;     // 0..7
    const int b    = blockIdx.x;

    __shared__ __align__(16) float kbuf[2][112][64];    // 57,344 B (double buffer)
    __shared__ __align__(16) float G_blk[2][14][8][8];  // 7,168 B Gram (i<j valid)
    __shared__ __align__(16) float al_lds[SEQ];         // alpha (absolute t)
    __shared__ __align__(16) float a_lds[SEQ];          // a output (absolute t)
    __shared__ __align__(16) float hbuf[8][2][64];      // per-wave h ping-pong
    __shared__ __align__(16) float sh[64];              // wave-0 scratch
    __shared__ __align__(16) float swr[8][64];          // wsum block reduce

    const float win = W_in[lane];

    // ---- producer constants (waves 1-7; harmless for wave 0) ----
    float4 wkr[16];
    {
        const float4* wk4 = (const float4*)(Wk + lane * 64);
#pragma unroll
        for (int i = 0; i < 16; ++i) wkr[i] = wk4[i];
    }
    const float wb = Wb[lane];
    const float bb = bbp[0];

    // produce 16 rows of group g into kbuf[buf] (R8 verbatim, validated).
    auto produce = [&](int g, int buf) {
        const int base = 672 - 112 * g;
        const int r0   = (wv - 1) * 16;
        float* hb0 = hbuf[wv][0];
        float* hb1 = hbuf[wv][1];
#pragma unroll 1
        for (int i = 0; i < 16; ++i) {
            const int r = r0 + i;
            const int s = base + r;
            const float xs = x[b * SEQ + s];
            const float pe = pos_emb[s * 64 + lane];
            const float h  = gelu_exact(fmaf(xs, win, pe));
            const float bdot = wave_allsum(h * wb);
            float* hb = (i & 1) ? hb1 : hb0;
            hb[lane] = h;
            WAVE_FENCE();
            const float4* h4 = (const float4*)hb;
            float kd = 0.f;
#pragma unroll
            for (int j = 0; j < 16; ++j) {
                float4 hv = h4[j];
                kd = fmaf(hv.x, wkr[j].x, kd);
                kd = fmaf(hv.y, wkr[j].y, kd);
                kd = fmaf(hv.z, wkr[j].z, kd);
                kd = fmaf(hv.w, wkr[j].w, kd);
            }
            float lam = wave_allsum(kd * kd);
            lam = fmaxf(lam, 1e-6f);
            const float beta = 1.0f / (1.0f + expf(-(bdot + bb)));
            const float al   = -expm1f(-beta * lam) / (lam + 1e-6f);
            kbuf[buf][r][lane] = kd;
            if (lane == 0) al_lds[s] = al;
        }
    };

    // gram8: wave wv's produced rows are exactly blocks beta = 2*(7-wv)+{0,1}.
    // 28 dots per block, 4 at a time via lane>>4 row batching (R9-validated
    // clamp pattern). Wave-local: only needs WAVE_FENCE after produce.
    auto gram8 = [&](int buf) {
#pragma unroll
        for (int blk = 0; blk < 2; ++blk) {
            const int beta = 2 * (7 - wv) + blk;
            const int rb   = 111 - 8 * beta;   // LDS row of block step 0
#pragma unroll
            for (int i = 0; i < 7; ++i) {
                const float4 kI = ((const float4*)kbuf[buf][rb - i])[lane & 15];
#pragma unroll
                for (int jb = i + 1; jb <= 7; jb += 4) {
                    const int j  = jb + (lane >> 4);
                    const int jc = (j <= 7) ? j : 7;
                    const float4 kJ = ((const float4*)kbuf[buf][rb - jc])[lane & 15];
                    const float gv = row16_allsum(dot4(kI, kJ));
                    if ((lane & 15) == 0 && j <= 7)
                        G_blk[buf][beta][i][j] = gv;
                }
            }
        }
    };

    // ---- phase 0: wave0 u-init || producers produce(0)+gram8(0) ----
    float4 uq = make_float4(0.f, 0.f, 0.f, 0.f);
    if (wv == 0) {
        const float h = gelu_exact(fmaf(x[b * SEQ + 783], win, pos_emb[783 * 64 + lane]));
        sh[lane] = h;
        WAVE_FENCE();
        float u = 0.f;
        const float4* wq4 = (const float4*)(Wq + lane * 64);
        const float4* h4  = (const float4*)sh;
#pragma unroll
        for (int i = 0; i < 16; ++i) {
            float4 hv = h4[i], qv = wq4[i];
            u = fmaf(hv.x, qv.x, u);
            u = fmaf(hv.y, qv.y, u);
            u = fmaf(hv.z, qv.z, u);
            u = fmaf(hv.w, qv.w, u);
        }
        WAVE_FENCE();
        sh[lane] = u;
        WAVE_FENCE();
        uq = ((const float4*)sh)[lane & 15];   // replicated slice layout
    } else {
        produce(0, 0);
        WAVE_FENCE();
        gram8(0);
    }
    __syncthreads();

    // oct-Gram scan block: 8 D-reductions (pipelined) + uniform-LDS Gram
    // reads + pure-VALU triangular solve + one u-update. Exact algebra:
    // d_i = D_i - sum_{j<i} a_j G_{ji};  a_i = alpha_i d_i.
    auto scan8 = [&](int buf, int T0, int beta) {
        const int rb = 111 - 8 * beta;
        const int T  = T0 - 8 * beta;
        const float4 k0 = ((const float4*)kbuf[buf][rb    ])[lane & 15];
        const float4 k1 = ((const float4*)kbuf[buf][rb - 1])[lane & 15];
        const float4 k2 = ((const float4*)kbuf[buf][rb - 2])[lane & 15];
        const float4 k3 = ((const float4*)kbuf[buf][rb - 3])[lane & 15];
        const float4 k4 = ((const float4*)kbuf[buf][rb - 4])[lane & 15];
        const float4 k5 = ((const float4*)kbuf[buf][rb - 5])[lane & 15];
        const float4 k6 = ((const float4*)kbuf[buf][rb - 6])[lane & 15];
        const float4 k7 = ((const float4*)kbuf[buf][rb - 7])[lane & 15];
        const float4 avH = *(const float4*)&al_lds[T - 3];  // al0=.w .. al3=.x
        const float4 avL = *(const float4*)&al_lds[T - 7];  // al4=.w .. al7=.x
        const float* Gb = &G_blk[buf][beta][0][0];
        const float g01 = Gb[1],  g02 = Gb[2],  g03 = Gb[3],  g04 = Gb[4];
        const float g05 = Gb[5],  g06 = Gb[6],  g07 = Gb[7];
        const float g12 = Gb[10], g13 = Gb[11], g14 = Gb[12], g15 = Gb[13];
        const float g16 = Gb[14], g17 = Gb[15];
        const float g23 = Gb[19], g24 = Gb[20], g25 = Gb[21], g26 = Gb[22];
        const float g27 = Gb[23];
        const float g34 = Gb[28], g35 = Gb[29], g36 = Gb[30], g37 = Gb[31];
        const float g45 = Gb[37], g46 = Gb[38], g47 = Gb[39];
        const float g56 = Gb[46], g57 = Gb[47];
        const float g67 = Gb[55];
        const float D0 = row16_allsum(dot4(uq, k0));
        const float D1 = row16_allsum(dot4(uq, k1));
        const float D2 = row16_allsum(dot4(uq, k2));
        const float D3 = row16_allsum(dot4(uq, k3));
        const float D4 = row16_allsum(dot4(uq, k4));
        const float D5 = row16_allsum(dot4(uq, k5));
        const float D6 = row16_allsum(dot4(uq, k6));
        const float D7 = row16_allsum(dot4(uq, k7));
        const float a0 = avH.w * D0;
        const float d1 = fmaf(-a0, g01, D1);
        const float a1 = avH.z * d1;
        const float d2 = fmaf(-a1, g12, fmaf(-a0, g02, D2));
        const float a2 = avH.y * d2;
        const float d3 = fmaf(-a2, g23, fmaf(-a1, g13, fmaf(-a0, g03, D3)));
        const float a3 = avH.x * d3;
        const float d4 = fmaf(-a3, g34, fmaf(-a2, g24, fmaf(-a1, g14, fmaf(-a0, g04, D4))));
        const float a4 = avL.w * d4;
        const float d5 = fmaf(-a4, g45, fmaf(-a3, g35, fmaf(-a2, g25, fmaf(-a1, g15, fmaf(-a0, g05, D5)))));
        const float a5 = avL.z * d5;
        const float d6 = fmaf(-a5, g56, fmaf(-a4, g46, fmaf(-a3, g36, fmaf(-a2, g26, fmaf(-a1, g16, fmaf(-a0, g06, D6))))));
        const float a6 = avL.y * d6;
        const float d7 = fmaf(-a6, g67, fmaf(-a5, g57, fmaf(-a4, g47, fmaf(-a3, g37, fmaf(-a2, g27, fmaf(-a1, g17, fmaf(-a0, g07, D7)))))));
        const float a7 = avL.x * d7;
        uq.x = fmaf(-a7, k7.x, fmaf(-a6, k6.x, fmaf(-a5, k5.x, fmaf(-a4, k4.x,
               fmaf(-a3, k3.x, fmaf(-a2, k2.x, fmaf(-a1, k1.x, fmaf(-a0, k0.x, uq.x))))))));
        uq.y = fmaf(-a7, k7.y, fmaf(-a6, k6.y, fmaf(-a5, k5.y, fmaf(-a4, k4.y,
               fmaf(-a3, k3.y, fmaf(-a2, k2.y, fmaf(-a1, k1.y, fmaf(-a0, k0.y, uq.y))))))));
        uq.z = fmaf(-a7, k7.z, fmaf(-a6, k6.z, fmaf(-a5, k5.z, fmaf(-a4, k4.z,
               fmaf(-a3, k3.z, fmaf(-a2, k2.z, fmaf(-a1, k1.z, fmaf(-a0, k0.z, uq.z))))))));
        uq.w = fmaf(-a7, k7.w, fmaf(-a6, k6.w, fmaf(-a5, k5.w, fmaf(-a4, k4.w,
               fmaf(-a3, k3.w, fmaf(-a2, k2.w, fmaf(-a1, k1.w, fmaf(-a0, k0.w, uq.w))))))));
        if (lane == 0) {
            *(float4*)&a_lds[T - 3] = make_float4(a3, a2, a1, a0);
            *(float4*)&a_lds[T - 7] = make_float4(a7, a6, a5, a4);
        }
    };

    // ---- main loop: wave0 scans group g; producers produce+gram group g+1 ----
#pragma unroll 1
    for (int g = 0; g < 7; ++g) {
        const int buf = g & 1;
        const int T0  = 783 - 112 * g;
        if (wv == 0) {
#pragma unroll 1
            for (int beta = 0; beta < 14; ++beta)
                scan8(buf, T0, beta);
        } else if (g < 6) {
            produce(g + 1, buf ^ 1);
            WAVE_FENCE();
            gram8(buf ^ 1);
        }
        __syncthreads();
    }

    // ---- wsum: all 8 waves, 98 rows each (R8 verbatim) ----
    float w = 0.f;
    {
        const int t0 = wv * 98;
#pragma unroll 2
        for (int i = 0; i < 98; ++i) {
            const int t = t0 + i;
            const float h = gelu_exact(fmaf(x[b * SEQ + t], win, pos_emb[t * 64 + lane]));
            w = fmaf(a_lds[t], h, w);
        }
    }
    swr[wv][lane] = w;
    __syncthreads();
    if (wv != 0) return;

    // ---- wave-0 epilogue: last = Wv*w -> LN -> logits (R8 verbatim) ----
    w = swr[0][lane] + swr[1][lane] + swr[2][lane] + swr[3][lane]
      + swr[4][lane] + swr[5][lane] + swr[6][lane] + swr[7][lane];
    sh[lane] = w;
    WAVE_FENCE();
    float last = 0.f;
    const float4* wv4 = (const float4*)(Wv + lane * 64);
    const float4* w4  = (const float4*)sh;
#pragma unroll
    for (int i = 0; i < 16; ++i) {
        float4 hv = w4[i], vv = wv4[i];
        last = fmaf(hv.x, vv.x, last);
        last = fmaf(hv.y, vv.y, last);
        last = fmaf(hv.z, vv.z, last);
        last = fmaf(hv.w, vv.w, last);
    }
    const float mu  = wave_allsum(last) * 0.015625f;
    const float dd  = last - mu;
    const float var = wave_allsum(dd * dd) * 0.015625f;
    const float ln  = dd / sqrtf(var + 1e-5f) * ln_g[lane] + ln_b[lane];
    WAVE_FENCE();
    sh[lane] = ln;
    WAVE_FENCE();
    if (lane < 10) {
        float acc = bc[lane];
        const float* wc = Wc + lane * 64;
#pragma unroll
        for (int j = 0; j < 64; ++j) acc = fmaf(wc[j], sh[j], acc);
        out[b * 10 + lane] = acc;
    }
}

extern "C" void kernel_launch(void* const* d_in, const int* in_sizes, int n_in,
                              void* d_out, int out_size, void* d_ws, size_t ws_size,
                              hipStream_t stream)
{
    const float* x       = (const float*)d_in[0];
    const float* W_in    = (const float*)d_in[1];
    const float* pos_emb = (const float*)d_in[2];
    const float* Wq      = (const float*)d_in[3];
    const float* Wk      = (const float*)d_in[4];
    const float* Wv      = (const float*)d_in[5];
    const float* Wb      = (const float*)d_in[6];
    const float* bb      = (const float*)d_in[7];
    const float* ln_g    = (const float*)d_in[8];
    const float* ln_b    = (const float*)d_in[9];
    const float* Wc      = (const float*)d_in[10];
    const float* bc      = (const float*)d_in[11];
    float* out = (float*)d_out;

    fused_all<<<BATCH, 512, 0, stream>>>(x, W_in, pos_emb, Wq, Wk, Wv, Wb, bb,
                                         ln_g, ln_b, Wc, bc, out);
}

// Round 11
// 106.818 us; speedup vs baseline: 3.0845x; 1.2272x over previous
//
#include <hip/hip_runtime.h>
#include <math.h>

#define DIM 64
#define SEQ 784
#define BATCH 256
// 7 groups x 112 rows; group split into 14 blocks of 8 steps.
// step m (0..111) -> t = T0 - m (T0 = 783-112g), LDS row r = 111 - m.

// ---------- cross-lane helpers (wave64 reduction via DPP) ----------
template <int CTRL>
__device__ __forceinline__ float dpp_add_step(float s) {
    int v = __builtin_amdgcn_update_dpp(0, __float_as_int(s), CTRL, 0xF, 0xF, false);
    return s + __int_as_float(v);
}

// Sum across all 64 lanes; result broadcast (uniform, via readlane 63).
__device__ __forceinline__ float wave_allsum(float x) {
    x = dpp_add_step<0xB1>(x);   // xor 1
    x = dpp_add_step<0x4E>(x);   // xor 2
    x = dpp_add_step<0x141>(x);  // row_half_mirror
    x = dpp_add_step<0x140>(x);  // row_mirror
    x = dpp_add_step<0x142>(x);  // row_bcast15
    x = dpp_add_step<0x143>(x);  // row_bcast31
    return __int_as_float(__builtin_amdgcn_readlane(__float_as_int(x), 63));
}

// 16-lane row allsum (replicated layout): 4 DPP steps, uniform result, no readlane.
__device__ __forceinline__ float row16_allsum(float x) {
    x = dpp_add_step<0xB1>(x);
    x = dpp_add_step<0x4E>(x);
    x = dpp_add_step<0x141>(x);
    x = dpp_add_step<0x140>(x);
    return x;
}

__device__ __forceinline__ float dot4(float4 a, float4 b) {
    return fmaf(a.w, b.w, fmaf(a.z, b.z, fmaf(a.y, b.y, a.x * b.x)));
}

__device__ __forceinline__ float gelu_exact(float v) {
    return 0.5f * v * (1.0f + erff(v * 0.70710678118654752440f));
}

// Zero-instruction wave-local LDS ordering (compile-time only; same-wave DS
// ops complete in order in HW). Validated R5-R10.
#define WAVE_FENCE()                                                \
    do {                                                            \
        __builtin_amdgcn_wave_barrier();                            \
        asm volatile("" ::: "memory");                              \
    } while (0)

// ---------- fused kernel: one block (8 waves) per batch ----------
// wave 0: scanner (oct-Gram blocks; Gram precomputed by producers)
// waves 1-7: produce(g+1) [batched phases A-E] then gram8(g+1).
__global__ __launch_bounds__(512, 1) void fused_all(
    const float* __restrict__ x, const float* __restrict__ W_in,
    const float* __restrict__ pos_emb, const float* __restrict__ Wq,
    const float* __restrict__ Wk, const float* __restrict__ Wv,
    const float* __restrict__ Wb, const float* __restrict__ bbp,
    const float* __restrict__ ln_g, const float* __restrict__ ln_b,
    const float* __restrict__ Wc, const float* __restrict__ bc,
    float* __restrict__ out)
{
    const int lane = threadIdx.x & 63;
    const int wv   = threadIdx.x >> 6;     // 0..7
    const int b    = blockIdx.x;

    __shared__ __align__(16) float kbuf[2][112][64];    // 57,344 B (double buffer)
    __shared__ __align__(16) float G_blk[2][14][8][8];  // 7,168 B Gram (i<j valid)
    __shared__ __align__(16) float al_lds[SEQ];         // alpha (absolute t)
    __shared__ __align__(16) float a_lds[SEQ];          // a output (absolute t)
    __shared__ __align__(16) float hb16[7][16][64];     // 28,672 B producer h rows
    __shared__ __align__(16) float sh[64];              // wave-0 scratch
    __shared__ __align__(16) float swr[8][64];          // wsum block reduce

    const float win = W_in[lane];

    // ---- producer constants (waves 1-7; harmless for wave 0) ----
    float4 wkr[16];
    {
        const float4* wk4 = (const float4*)(Wk + lane * 64);
#pragma unroll
        for (int i = 0; i < 16; ++i) wkr[i] = wk4[i];
    }
    const float wb = Wb[lane];
    const float bb = bbp[0];
    const float4 wb4 = ((const float4*)Wb)[lane & 15];   // replicated slice
    (void)wb;

    // produce 16 rows of group g into kbuf[buf] -- BATCHED phases:
    // A: 16 h rows (ILP) -> LDS; B: 16 bdots via 4 replicated row16 calls;
    // C: 16 GEMVs (pure throughput) -> kbuf; D: 16 lams via 4 calls;
    // E: alphas 4-parallel across lane groups. Same per-row math as R8.
    auto produce = [&](int g, int buf) {
        const int base = 672 - 112 * g;
        const int r0   = (wv - 1) * 16;
        float (*hw)[64] = hb16[wv - 1];
        // ---- A ----
#pragma unroll
        for (int i = 0; i < 16; ++i) {
            const int s = base + r0 + i;
            const float h = gelu_exact(fmaf(x[b * SEQ + s], win, pos_emb[s * 64 + lane]));
            hw[i][lane] = h;
        }
        WAVE_FENCE();
        // ---- B ---- (lane-group gr handles row ib*4+gr)
        float bd[4];
#pragma unroll
        for (int ib = 0; ib < 4; ++ib) {
            const int i = ib * 4 + (lane >> 4);
            const float4 h4 = ((const float4*)hw[i])[lane & 15];
            bd[ib] = row16_allsum(dot4(h4, wb4));
        }
        // ---- C ----
#pragma unroll
        for (int i = 0; i < 16; ++i) {
            const float4* h4 = (const float4*)hw[i];
            float acc = 0.f;
#pragma unroll
            for (int j = 0; j < 16; ++j) {
                const float4 hv = h4[j], wk = wkr[j];
                acc = fmaf(hv.x, wk.x, acc);
                acc = fmaf(hv.y, wk.y, acc);
                acc = fmaf(hv.z, wk.z, acc);
                acc = fmaf(hv.w, wk.w, acc);
            }
            kbuf[buf][r0 + i][lane] = acc;
        }
        WAVE_FENCE();
        // ---- D + E ----
#pragma unroll
        for (int ib = 0; ib < 4; ++ib) {
            const int i = ib * 4 + (lane >> 4);
            const float4 k4 = ((const float4*)kbuf[buf][r0 + i])[lane & 15];
            float lam = row16_allsum(dot4(k4, k4));
            lam = fmaxf(lam, 1e-6f);
            const float beta = 1.0f / (1.0f + expf(-(bd[ib] + bb)));
            const float al   = -expm1f(-beta * lam) / (lam + 1e-6f);
            if ((lane & 15) == 0) al_lds[base + r0 + i] = al;
        }
    };

    // gram8: wave wv's produced rows are exactly blocks beta = 2*(7-wv)+{0,1}.
    // (R10 verbatim, validated absmax 0.0)
    auto gram8 = [&](int buf) {
#pragma unroll
        for (int blk = 0; blk < 2; ++blk) {
            const int beta = 2 * (7 - wv) + blk;
            const int rb   = 111 - 8 * beta;   // LDS row of block step 0
#pragma unroll
            for (int i = 0; i < 7; ++i) {
                const float4 kI = ((const float4*)kbuf[buf][rb - i])[lane & 15];
#pragma unroll
                for (int jb = i + 1; jb <= 7; jb += 4) {
                    const int j  = jb + (lane >> 4);
                    const int jc = (j <= 7) ? j : 7;
                    const float4 kJ = ((const float4*)kbuf[buf][rb - jc])[lane & 15];
                    const float gv = row16_allsum(dot4(kI, kJ));
                    if ((lane & 15) == 0 && j <= 7)
                        G_blk[buf][beta][i][j] = gv;
                }
            }
        }
    };

    // ---- phase 0: wave0 u-init || producers produce(0)+gram8(0) ----
    float4 uq = make_float4(0.f, 0.f, 0.f, 0.f);
    if (wv == 0) {
        const float h = gelu_exact(fmaf(x[b * SEQ + 783], win, pos_emb[783 * 64 + lane]));
        sh[lane] = h;
        WAVE_FENCE();
        float u = 0.f;
        const float4* wq4 = (const float4*)(Wq + lane * 64);
        const float4* h4  = (const float4*)sh;
#pragma unroll
        for (int i = 0; i < 16; ++i) {
            float4 hv = h4[i], qv = wq4[i];
            u = fmaf(hv.x, qv.x, u);
            u = fmaf(hv.y, qv.y, u);
            u = fmaf(hv.z, qv.z, u);
            u = fmaf(hv.w, qv.w, u);
        }
        WAVE_FENCE();
        sh[lane] = u;
        WAVE_FENCE();
        uq = ((const float4*)sh)[lane & 15];   // replicated slice layout
    } else {
        produce(0, 0);
        WAVE_FENCE();
        gram8(0);
    }
    __syncthreads();

    // oct-Gram scan block (R10 verbatim, validated absmax 0.0)
    auto scan8 = [&](int buf, int T0, int beta) {
        const int rb = 111 - 8 * beta;
        const int T  = T0 - 8 * beta;
        const float4 k0 = ((const float4*)kbuf[buf][rb    ])[lane & 15];
        const float4 k1 = ((const float4*)kbuf[buf][rb - 1])[lane & 15];
        const float4 k2 = ((const float4*)kbuf[buf][rb - 2])[lane & 15];
        const float4 k3 = ((const float4*)kbuf[buf][rb - 3])[lane & 15];
        const float4 k4 = ((const float4*)kbuf[buf][rb - 4])[lane & 15];
        const float4 k5 = ((const float4*)kbuf[buf][rb - 5])[lane & 15];
        const float4 k6 = ((const float4*)kbuf[buf][rb - 6])[lane & 15];
        const float4 k7 = ((const float4*)kbuf[buf][rb - 7])[lane & 15];
        const float4 avH = *(const float4*)&al_lds[T - 3];  // al0=.w .. al3=.x
        const float4 avL = *(const float4*)&al_lds[T - 7];  // al4=.w .. al7=.x
        const float* Gb = &G_blk[buf][beta][0][0];
        const float g01 = Gb[1],  g02 = Gb[2],  g03 = Gb[3],  g04 = Gb[4];
        const float g05 = Gb[5],  g06 = Gb[6],  g07 = Gb[7];
        const float g12 = Gb[10], g13 = Gb[11], g14 = Gb[12], g15 = Gb[13];
        const float g16 = Gb[14], g17 = Gb[15];
        const float g23 = Gb[19], g24 = Gb[20], g25 = Gb[21], g26 = Gb[22];
        const float g27 = Gb[23];
        const float g34 = Gb[28], g35 = Gb[29], g36 = Gb[30], g37 = Gb[31];
        const float g45 = Gb[37], g46 = Gb[38], g47 = Gb[39];
        const float g56 = Gb[46], g57 = Gb[47];
        const float g67 = Gb[55];
        const float D0 = row16_allsum(dot4(uq, k0));
        const float D1 = row16_allsum(dot4(uq, k1));
        const float D2 = row16_allsum(dot4(uq, k2));
        const float D3 = row16_allsum(dot4(uq, k3));
        const float D4 = row16_allsum(dot4(uq, k4));
        const float D5 = row16_allsum(dot4(uq, k5));
        const float D6 = row16_allsum(dot4(uq, k6));
        const float D7 = row16_allsum(dot4(uq, k7));
        const float a0 = avH.w * D0;
        const float d1 = fmaf(-a0, g01, D1);
        const float a1 = avH.z * d1;
        const float d2 = fmaf(-a1, g12, fmaf(-a0, g02, D2));
        const float a2 = avH.y * d2;
        const float d3 = fmaf(-a2, g23, fmaf(-a1, g13, fmaf(-a0, g03, D3)));
        const float a3 = avH.x * d3;
        const float d4 = fmaf(-a3, g34, fmaf(-a2, g24, fmaf(-a1, g14, fmaf(-a0, g04, D4))));
        const float a4 = avL.w * d4;
        const float d5 = fmaf(-a4, g45, fmaf(-a3, g35, fmaf(-a2, g25, fmaf(-a1, g15, fmaf(-a0, g05, D5)))));
        const float a5 = avL.z * d5;
        const float d6 = fmaf(-a5, g56, fmaf(-a4, g46, fmaf(-a3, g36, fmaf(-a2, g26, fmaf(-a1, g16, fmaf(-a0, g06, D6))))));
        const float a6 = avL.y * d6;
        const float d7 = fmaf(-a6, g67, fmaf(-a5, g57, fmaf(-a4, g47, fmaf(-a3, g37, fmaf(-a2, g27, fmaf(-a1, g17, fmaf(-a0, g07, D7)))))));
        const float a7 = avL.x * d7;
        uq.x = fmaf(-a7, k7.x, fmaf(-a6, k6.x, fmaf(-a5, k5.x, fmaf(-a4, k4.x,
               fmaf(-a3, k3.x, fmaf(-a2, k2.x, fmaf(-a1, k1.x, fmaf(-a0, k0.x, uq.x))))))));
        uq.y = fmaf(-a7, k7.y, fmaf(-a6, k6.y, fmaf(-a5, k5.y, fmaf(-a4, k4.y,
               fmaf(-a3, k3.y, fmaf(-a2, k2.y, fmaf(-a1, k1.y, fmaf(-a0, k0.y, uq.y))))))));
        uq.z = fmaf(-a7, k7.z, fmaf(-a6, k6.z, fmaf(-a5, k5.z, fmaf(-a4, k4.z,
               fmaf(-a3, k3.z, fmaf(-a2, k2.z, fmaf(-a1, k1.z, fmaf(-a0, k0.z, uq.z))))))));
        uq.w = fmaf(-a7, k7.w, fmaf(-a6, k6.w, fmaf(-a5, k5.w, fmaf(-a4, k4.w,
               fmaf(-a3, k3.w, fmaf(-a2, k2.w, fmaf(-a1, k1.w, fmaf(-a0, k0.w, uq.w))))))));
        if (lane == 0) {
            *(float4*)&a_lds[T - 3] = make_float4(a3, a2, a1, a0);
            *(float4*)&a_lds[T - 7] = make_float4(a7, a6, a5, a4);
        }
    };

    // ---- main loop: wave0 scans group g; producers produce+gram group g+1 ----
#pragma unroll 1
    for (int g = 0; g < 7; ++g) {
        const int buf = g & 1;
        const int T0  = 783 - 112 * g;
        if (wv == 0) {
#pragma unroll 1
            for (int beta = 0; beta < 14; ++beta)
                scan8(buf, T0, beta);
        } else if (g < 6) {
            produce(g + 1, buf ^ 1);
            WAVE_FENCE();
            gram8(buf ^ 1);
        }
        __syncthreads();
    }

    // ---- wsum: all 8 waves, 98 rows each (R8 verbatim) ----
    float w = 0.f;
    {
        const int t0 = wv * 98;
#pragma unroll 2
        for (int i = 0; i < 98; ++i) {
            const int t = t0 + i;
            const float h = gelu_exact(fmaf(x[b * SEQ + t], win, pos_emb[t * 64 + lane]));
            w = fmaf(a_lds[t], h, w);
        }
    }
    swr[wv][lane] = w;
    __syncthreads();
    if (wv != 0) return;

    // ---- wave-0 epilogue: last = Wv*w -> LN -> logits (R8 verbatim) ----
    w = swr[0][lane] + swr[1][lane] + swr[2][lane] + swr[3][lane]
      + swr[4][lane] + swr[5][lane] + swr[6][lane] + swr[7][lane];
    sh[lane] = w;
    WAVE_FENCE();
    float last = 0.f;
    const float4* wv4 = (const float4*)(Wv + lane * 64);
    const float4* w4  = (const float4*)sh;
#pragma unroll
    for (int i = 0; i < 16; ++i) {
        float4 hv = w4[i], vv = wv4[i];
        last = fmaf(hv.x, vv.x, last);
        last = fmaf(hv.y, vv.y, last);
        last = fmaf(hv.z, vv.z, last);
        last = fmaf(hv.w, vv.w, last);
    }
    const float mu  = wave_allsum(last) * 0.015625f;
    const float dd  = last - mu;
    const float var = wave_allsum(dd * dd) * 0.015625f;
    const float ln  = dd / sqrtf(var + 1e-5f) * ln_g[lane] + ln_b[lane];
    WAVE_FENCE();
    sh[lane] = ln;
    WAVE_FENCE();
    if (lane < 10) {
        float acc = bc[lane];
        const float* wc = Wc + lane * 64;
#pragma unroll
        for (int j = 0; j < 64; ++j) acc = fmaf(wc[j], sh[j], acc);
        out[b * 10 + lane] = acc;
    }
}

extern "C" void kernel_launch(void* const* d_in, const int* in_sizes, int n_in,
                              void* d_out, int out_size, void* d_ws, size_t ws_size,
                              hipStream_t stream)
{
    const float* x       = (const float*)d_in[0];
    const float* W_in    = (const float*)d_in[1];
    const float* pos_emb = (const float*)d_in[2];
    const float* Wq      = (const float*)d_in[3];
    const float* Wk      = (const float*)d_in[4];
    const float* Wv      = (const float*)d_in[5];
    const float* Wb      = (const float*)d_in[6];
    const float* bb      = (const float*)d_in[7];
    const float* ln_g    = (const float*)d_in[8];
    const float* ln_b    = (const float*)d_in[9];
    const float* Wc      = (const float*)d_in[10];
    const float* bc      = (const float*)d_in[11];
    float* out = (float*)d_out;

    fused_all<<<BATCH, 512, 0, stream>>>(x, W_in, pos_emb, Wq, Wk, Wv, Wb, bb,
                                         ln_g, ln_b, Wc, bc, out);
}

// Round 12
// 89.853 us; speedup vs baseline: 3.6669x; 1.1888x over previous
//
#include <hip/hip_runtime.h>
#include <math.h>

#define DIM 64
#define SEQ 784
#define BATCH 256
// 7 groups x 112 rows; group split into 14 blocks of 8 steps.
// step m (0..111) -> t = T0 - m (T0 = 783-112g), LDS row r = 111 - m.
// group g covers t in [672-112g, 783-112g]; base(g) = 672-112g.

// ---------- cross-lane helpers (wave64 reduction via DPP) ----------
template <int CTRL>
__device__ __forceinline__ float dpp_add_step(float s) {
    int v = __builtin_amdgcn_update_dpp(0, __float_as_int(s), CTRL, 0xF, 0xF, false);
    return s + __int_as_float(v);
}

// Sum across all 64 lanes; result broadcast (uniform, via readlane 63).
__device__ __forceinline__ float wave_allsum(float x) {
    x = dpp_add_step<0xB1>(x);   // xor 1
    x = dpp_add_step<0x4E>(x);   // xor 2
    x = dpp_add_step<0x141>(x);  // row_half_mirror
    x = dpp_add_step<0x140>(x);  // row_mirror
    x = dpp_add_step<0x142>(x);  // row_bcast15
    x = dpp_add_step<0x143>(x);  // row_bcast31
    return __int_as_float(__builtin_amdgcn_readlane(__float_as_int(x), 63));
}

// 16-lane row allsum (replicated layout): 4 DPP steps, uniform result, no readlane.
__device__ __forceinline__ float row16_allsum(float x) {
    x = dpp_add_step<0xB1>(x);
    x = dpp_add_step<0x4E>(x);
    x = dpp_add_step<0x141>(x);
    x = dpp_add_step<0x140>(x);
    return x;
}

__device__ __forceinline__ float dot4(float4 a, float4 b) {
    return fmaf(a.w, b.w, fmaf(a.z, b.z, fmaf(a.y, b.y, a.x * b.x)));
}

__device__ __forceinline__ float gelu_exact(float v) {
    return 0.5f * v * (1.0f + erff(v * 0.70710678118654752440f));
}

// Zero-instruction wave-local LDS ordering (compile-time only; same-wave DS
// ops complete in order in HW). Validated R5-R11.
#define WAVE_FENCE()                                                \
    do {                                                            \
        __builtin_amdgcn_wave_barrier();                            \
        asm volatile("" ::: "memory");                              \
    } while (0)

// ---------- fused kernel: one block (8 waves) per batch ----------
// wave 0: scanner (oct-Gram blocks; Gram precomputed by producers)
// waves 1-7: wsum(g-1) from stored h, then produce(g+1) [phases A-E], gram8.
__global__ __launch_bounds__(512, 1) void fused_all(
    const float* __restrict__ x, const float* __restrict__ W_in,
    const float* __restrict__ pos_emb, const float* __restrict__ Wq,
    const float* __restrict__ Wk, const float* __restrict__ Wv,
    const float* __restrict__ Wb, const float* __restrict__ bbp,
    const float* __restrict__ ln_g, const float* __restrict__ ln_b,
    const float* __restrict__ Wc, const float* __restrict__ bc,
    float* __restrict__ out)
{
    const int lane = threadIdx.x & 63;
    const int wv   = threadIdx.x >> 6;     // 0..7
    const int b    = blockIdx.x;

    __shared__ __align__(16) float kbuf[2][112][64];     // 57,344 B (double buffer)
    __shared__ __align__(16) float G_blk[2][14][8][8];   // 7,168 B Gram (i<j valid)
    __shared__ __align__(16) float al_lds[SEQ];          // alpha (absolute t)
    __shared__ __align__(16) float a_lds[SEQ];           // a output (absolute t)
    __shared__ __align__(16) float hb16[2][7][16][64];   // 57,344 B h rows (dbuf)
    __shared__ __align__(16) float sh[64];               // wave-0 scratch
    __shared__ __align__(16) float swr[8][64];           // wsum block reduce

    const float win = W_in[lane];

    // ---- producer constants (waves 1-7; harmless for wave 0) ----
    float4 wkr[16];
    {
        const float4* wk4 = (const float4*)(Wk + lane * 64);
#pragma unroll
        for (int i = 0; i < 16; ++i) wkr[i] = wk4[i];
    }
    const float bb = bbp[0];
    const float4 wb4 = ((const float4*)Wb)[lane & 15];   // replicated slice

    // produce 16 rows of group g into kbuf[buf], h rows into hb16[g&1].
    // Batched phases A-E (R11 verbatim math, validated absmax ~1e-6).
    auto produce = [&](int g, int buf) {
        const int base = 672 - 112 * g;
        const int r0   = (wv - 1) * 16;
        float (*hw)[64] = hb16[g & 1][wv - 1];
        // ---- A ----
#pragma unroll
        for (int i = 0; i < 16; ++i) {
            const int s = base + r0 + i;
            const float h = gelu_exact(fmaf(x[b * SEQ + s], win, pos_emb[s * 64 + lane]));
            hw[i][lane] = h;
        }
        WAVE_FENCE();
        // ---- B ---- (lane-group gr handles row ib*4+gr)
        float bd[4];
#pragma unroll
        for (int ib = 0; ib < 4; ++ib) {
            const int i = ib * 4 + (lane >> 4);
            const float4 h4 = ((const float4*)hw[i])[lane & 15];
            bd[ib] = row16_allsum(dot4(h4, wb4));
        }
        // ---- C ----
#pragma unroll
        for (int i = 0; i < 16; ++i) {
            const float4* h4 = (const float4*)hw[i];
            float acc = 0.f;
#pragma unroll
            for (int j = 0; j < 16; ++j) {
                const float4 hv = h4[j], wk = wkr[j];
                acc = fmaf(hv.x, wk.x, acc);
                acc = fmaf(hv.y, wk.y, acc);
                acc = fmaf(hv.z, wk.z, acc);
                acc = fmaf(hv.w, wk.w, acc);
            }
            kbuf[buf][r0 + i][lane] = acc;
        }
        WAVE_FENCE();
        // ---- D + E ----
#pragma unroll
        for (int ib = 0; ib < 4; ++ib) {
            const int i = ib * 4 + (lane >> 4);
            const float4 k4 = ((const float4*)kbuf[buf][r0 + i])[lane & 15];
            float lam = row16_allsum(dot4(k4, k4));
            lam = fmaxf(lam, 1e-6f);
            const float beta = 1.0f / (1.0f + expf(-(bd[ib] + bb)));
            const float al   = -expm1f(-beta * lam) / (lam + 1e-6f);
            if ((lane & 15) == 0) al_lds[base + r0 + i] = al;
        }
    };

    // gram8 (R10 verbatim, validated): wave wv owns blocks beta=2*(7-wv)+{0,1}.
    auto gram8 = [&](int buf) {
#pragma unroll
        for (int blk = 0; blk < 2; ++blk) {
            const int beta = 2 * (7 - wv) + blk;
            const int rb   = 111 - 8 * beta;   // LDS row of block step 0
#pragma unroll
            for (int i = 0; i < 7; ++i) {
                const float4 kI = ((const float4*)kbuf[buf][rb - i])[lane & 15];
#pragma unroll
                for (int jb = i + 1; jb <= 7; jb += 4) {
                    const int j  = jb + (lane >> 4);
                    const int jc = (j <= 7) ? j : 7;
                    const float4 kJ = ((const float4*)kbuf[buf][rb - jc])[lane & 15];
                    const float gv = row16_allsum(dot4(kI, kJ));
                    if ((lane & 15) == 0 && j <= 7)
                        G_blk[buf][beta][i][j] = gv;
                }
            }
        }
    };

    // wsum for this wave's 16 rows of group g, from STORED h (no gelu/loads).
    // a_lds(g) was completed by the scanner last period (barrier-ordered);
    // hb16[g&1] still holds h(g): the same-parity overwrite by produce(g+2)
    // happens AFTER this read in the same wave's program order.
    float w = 0.f;
    auto wsum16 = [&](int g) {
        const int base = 672 - 112 * g;
        const int r0   = (wv - 1) * 16;
        const float (*hw)[64] = hb16[g & 1][wv - 1];
#pragma unroll
        for (int i = 0; i < 16; ++i)
            w = fmaf(a_lds[base + r0 + i], hw[i][lane], w);
    };

    // ---- phase 0: wave0 u-init || producers produce(0)+gram8(0) ----
    float4 uq = make_float4(0.f, 0.f, 0.f, 0.f);
    if (wv == 0) {
        const float h = gelu_exact(fmaf(x[b * SEQ + 783], win, pos_emb[783 * 64 + lane]));
        sh[lane] = h;
        WAVE_FENCE();
        float u = 0.f;
        const float4* wq4 = (const float4*)(Wq + lane * 64);
        const float4* h4  = (const float4*)sh;
#pragma unroll
        for (int i = 0; i < 16; ++i) {
            float4 hv = h4[i], qv = wq4[i];
            u = fmaf(hv.x, qv.x, u);
            u = fmaf(hv.y, qv.y, u);
            u = fmaf(hv.z, qv.z, u);
            u = fmaf(hv.w, qv.w, u);
        }
        WAVE_FENCE();
        sh[lane] = u;
        WAVE_FENCE();
        uq = ((const float4*)sh)[lane & 15];   // replicated slice layout
    } else {
        produce(0, 0);
        WAVE_FENCE();
        gram8(0);
    }
    __syncthreads();

    // oct-Gram scan block (R10 verbatim, validated)
    auto scan8 = [&](int buf, int T0, int beta) {
        const int rb = 111 - 8 * beta;
        const int T  = T0 - 8 * beta;
        const float4 k0 = ((const float4*)kbuf[buf][rb    ])[lane & 15];
        const float4 k1 = ((const float4*)kbuf[buf][rb - 1])[lane & 15];
        const float4 k2 = ((const float4*)kbuf[buf][rb - 2])[lane & 15];
        const float4 k3 = ((const float4*)kbuf[buf][rb - 3])[lane & 15];
        const float4 k4 = ((const float4*)kbuf[buf][rb - 4])[lane & 15];
        const float4 k5 = ((const float4*)kbuf[buf][rb - 5])[lane & 15];
        const float4 k6 = ((const float4*)kbuf[buf][rb - 6])[lane & 15];
        const float4 k7 = ((const float4*)kbuf[buf][rb - 7])[lane & 15];
        const float4 avH = *(const float4*)&al_lds[T - 3];  // al0=.w .. al3=.x
        const float4 avL = *(const float4*)&al_lds[T - 7];  // al4=.w .. al7=.x
        const float* Gb = &G_blk[buf][beta][0][0];
        const float g01 = Gb[1],  g02 = Gb[2],  g03 = Gb[3],  g04 = Gb[4];
        const float g05 = Gb[5],  g06 = Gb[6],  g07 = Gb[7];
        const float g12 = Gb[10], g13 = Gb[11], g14 = Gb[12], g15 = Gb[13];
        const float g16 = Gb[14], g17 = Gb[15];
        const float g23 = Gb[19], g24 = Gb[20], g25 = Gb[21], g26 = Gb[22];
        const float g27 = Gb[23];
        const float g34 = Gb[28], g35 = Gb[29], g36 = Gb[30], g37 = Gb[31];
        const float g45 = Gb[37], g46 = Gb[38], g47 = Gb[39];
        const float g56 = Gb[46], g57 = Gb[47];
        const float g67 = Gb[55];
        const float D0 = row16_allsum(dot4(uq, k0));
        const float D1 = row16_allsum(dot4(uq, k1));
        const float D2 = row16_allsum(dot4(uq, k2));
        const float D3 = row16_allsum(dot4(uq, k3));
        const float D4 = row16_allsum(dot4(uq, k4));
        const float D5 = row16_allsum(dot4(uq, k5));
        const float D6 = row16_allsum(dot4(uq, k6));
        const float D7 = row16_allsum(dot4(uq, k7));
        const float a0 = avH.w * D0;
        const float d1 = fmaf(-a0, g01, D1);
        const float a1 = avH.z * d1;
        const float d2 = fmaf(-a1, g12, fmaf(-a0, g02, D2));
        const float a2 = avH.y * d2;
        const float d3 = fmaf(-a2, g23, fmaf(-a1, g13, fmaf(-a0, g03, D3)));
        const float a3 = avH.x * d3;
        const float d4 = fmaf(-a3, g34, fmaf(-a2, g24, fmaf(-a1, g14, fmaf(-a0, g04, D4))));
        const float a4 = avL.w * d4;
        const float d5 = fmaf(-a4, g45, fmaf(-a3, g35, fmaf(-a2, g25, fmaf(-a1, g15, fmaf(-a0, g05, D5)))));
        const float a5 = avL.z * d5;
        const float d6 = fmaf(-a5, g56, fmaf(-a4, g46, fmaf(-a3, g36, fmaf(-a2, g26, fmaf(-a1, g16, fmaf(-a0, g06, D6))))));
        const float a6 = avL.y * d6;
        const float d7 = fmaf(-a6, g67, fmaf(-a5, g57, fmaf(-a4, g47, fmaf(-a3, g37, fmaf(-a2, g27, fmaf(-a1, g17, fmaf(-a0, g07, D7)))))));
        const float a7 = avL.x * d7;
        uq.x = fmaf(-a7, k7.x, fmaf(-a6, k6.x, fmaf(-a5, k5.x, fmaf(-a4, k4.x,
               fmaf(-a3, k3.x, fmaf(-a2, k2.x, fmaf(-a1, k1.x, fmaf(-a0, k0.x, uq.x))))))));
        uq.y = fmaf(-a7, k7.y, fmaf(-a6, k6.y, fmaf(-a5, k5.y, fmaf(-a4, k4.y,
               fmaf(-a3, k3.y, fmaf(-a2, k2.y, fmaf(-a1, k1.y, fmaf(-a0, k0.y, uq.y))))))));
        uq.z = fmaf(-a7, k7.z, fmaf(-a6, k6.z, fmaf(-a5, k5.z, fmaf(-a4, k4.z,
               fmaf(-a3, k3.z, fmaf(-a2, k2.z, fmaf(-a1, k1.z, fmaf(-a0, k0.z, uq.z))))))));
        uq.w = fmaf(-a7, k7.w, fmaf(-a6, k6.w, fmaf(-a5, k5.w, fmaf(-a4, k4.w,
               fmaf(-a3, k3.w, fmaf(-a2, k2.w, fmaf(-a1, k1.w, fmaf(-a0, k0.w, uq.w))))))));
        if (lane == 0) {
            *(float4*)&a_lds[T - 3] = make_float4(a3, a2, a1, a0);
            *(float4*)&a_lds[T - 7] = make_float4(a7, a6, a5, a4);
        }
    };

    // ---- main loop: wave0 scans g; producers wsum(g-1) + produce/gram(g+1) ----
#pragma unroll 1
    for (int g = 0; g < 7; ++g) {
        const int buf = g & 1;
        const int T0  = 783 - 112 * g;
        if (wv == 0) {
#pragma unroll 1
            for (int beta = 0; beta < 14; ++beta)
                scan8(buf, T0, beta);
        } else {
            if (g >= 1) wsum16(g - 1);
            if (g < 6) {
                produce(g + 1, buf ^ 1);
                WAVE_FENCE();
                gram8(buf ^ 1);
            }
        }
        __syncthreads();
    }

    // ---- tail: producers wsum group 6 (a(6) barrier-ordered; h(6) in hb16[0]) ----
    if (wv != 0) wsum16(6);
    swr[wv][lane] = (wv == 0) ? 0.f : w;
    __syncthreads();
    if (wv != 0) return;

    // ---- wave-0 epilogue: last = Wv*w -> LN -> logits (R8 verbatim) ----
    w = swr[0][lane] + swr[1][lane] + swr[2][lane] + swr[3][lane]
      + swr[4][lane] + swr[5][lane] + swr[6][lane] + swr[7][lane];
    sh[lane] = w;
    WAVE_FENCE();
    float last = 0.f;
    const float4* wv4 = (const float4*)(Wv + lane * 64);
    const float4* w4  = (const float4*)sh;
#pragma unroll
    for (int i = 0; i < 16; ++i) {
        float4 hv = w4[i], vv = wv4[i];
        last = fmaf(hv.x, vv.x, last);
        last = fmaf(hv.y, vv.y, last);
        last = fmaf(hv.z, vv.z, last);
        last = fmaf(hv.w, vv.w, last);
    }
    const float mu  = wave_allsum(last) * 0.015625f;
    const float dd  = last - mu;
    const float var = wave_allsum(dd * dd) * 0.015625f;
    const float ln  = dd / sqrtf(var + 1e-5f) * ln_g[lane] + ln_b[lane];
    WAVE_FENCE();
    sh[lane] = ln;
    WAVE_FENCE();
    if (lane < 10) {
        float acc = bc[lane];
        const float* wc = Wc + lane * 64;
#pragma unroll
        for (int j = 0; j < 64; ++j) acc = fmaf(wc[j], sh[j], acc);
        out[b * 10 + lane] = acc;
    }
}

extern "C" void kernel_launch(void* const* d_in, const int* in_sizes, int n_in,
                              void* d_out, int out_size, void* d_ws, size_t ws_size,
                              hipStream_t stream)
{
    const float* x       = (const float*)d_in[0];
    const float* W_in    = (const float*)d_in[1];
    const float* pos_emb = (const float*)d_in[2];
    const float* Wq      = (const float*)d_in[3];
    const float* Wk      = (const float*)d_in[4];
    const float* Wv      = (const float*)d_in[5];
    const float* Wb      = (const float*)d_in[6];
    const float* bb      = (const float*)d_in[7];
    const float* ln_g    = (const float*)d_in[8];
    const float* ln_b    = (const float*)d_in[9];
    const float* Wc      = (const float*)d_in[10];
    const float* bc      = (const float*)d_in[11];
    float* out = (float*)d_out;

    fused_all<<<BATCH, 512, 0, stream>>>(x, W_in, pos_emb, Wq, Wk, Wv, Wb, bb,
                                         ln_g, ln_b, Wc, bc, out);
}